// Round 15
// baseline (183.681 us; speedup 1.0000x reference)
//
#include <hip/hip_runtime.h>
#include <hip/hip_fp16.h>
#include <math.h>

#define NS 64
#define NV 16
#define NHS 32
#define NHV 16

// den_scan geometry (unchanged)
#define RANGES 8
#define SPLITS 32
#define DP_STRIDE 50176

__device__ __forceinline__ float silu_f(float x){ return x * (1.0f / (1.0f + __expf(-x))); }

__device__ __forceinline__ float packh2(float a, float b){
    __half2 h = __floats2half2_rn(a, b);
    return __uint_as_float(*(unsigned*)&h);
}
__device__ __forceinline__ float2 unpackh2(float w){
    __half2 h = *(__half2*)&w;
    return __half22float2(h);
}

// Per-node precompute: pack[n] = 32B = {A fp32, ff[9]+pos[3] as fp16}
// 4 threads per node, H-SPLIT: thread q owns scalar rows q*8+i and vector
// rows q*4+j. Rows are independent (silu per row, linear sum after), so the
// only cross-lane op is one 2-step shfl reduce at the end. Node data in VGPRs
// (4 lanes/cache line -> ideal coalescing); weight loads shared by 16 lanes.
__global__ __launch_bounds__(256) void node_pack_kernel(
    const float* __restrict__ from_s, const float* __restrict__ from_v,
    const float* __restrict__ from_fr, const float* __restrict__ from_p,
    const float* __restrict__ to_s, const float* __restrict__ to_v,
    const float* __restrict__ to_fr, const float* __restrict__ to_p,
    const float* __restrict__ Wfs, const float* __restrict__ Wts,
    const float* __restrict__ Wfv, const float* __restrict__ Wtv,
    const float* __restrict__ Wattn,
    float* __restrict__ packA, float* __restrict__ packB,
    int N)
{
    const int side = blockIdx.y;
    const float* node_s = side ? to_s  : from_s;
    const float* node_v = side ? to_v  : from_v;
    const float* frame  = side ? to_fr : from_fr;
    const float* pos    = side ? to_p  : from_p;
    const float* Ws     = side ? Wts   : Wfs;
    const float* Wv     = side ? Wtv   : Wfv;
    const int    s_off  = side ? 32 : 0;
    const int    v_off  = side ? 115 : 64;
    float*       pack   = side ? packB : packA;

    const int t = blockIdx.x * 256 + threadIdx.x;
    const int n = t >> 2;          // node
    const int q = t & 3;           // row-quarter
    if (n >= N) return;

    // ---- node s -> registers (4 lanes share each cache line) ----
    float4 sv[16];
    {
        const float4* sp = (const float4*)(node_s + (size_t)n * NS);
        #pragma unroll
        for (int i = 0; i < 16; i++) sv[i] = sp[i];
    }

    // ---- scalar GEMV: rows h = q*8 .. q*8+7 ----
    float acc = 0.0f;
    #pragma unroll 2
    for (int i = 0; i < 8; i++){
        const int h = q * 8 + i;
        const float4* wr = (const float4*)(Ws + h * NS);
        float e0 = 0.f, e1 = 0.f, e2 = 0.f, e3 = 0.f;
        #pragma unroll
        for (int k = 0; k < 16; k += 4){
            float4 w0 = wr[k], w1 = wr[k+1], w2 = wr[k+2], w3 = wr[k+3];
            e0 += sv[k].x   * w0.x + sv[k].y   * w0.y + sv[k].z   * w0.z + sv[k].w   * w0.w;
            e1 += sv[k+1].x * w1.x + sv[k+1].y * w1.y + sv[k+1].z * w1.z + sv[k+1].w * w1.w;
            e2 += sv[k+2].x * w2.x + sv[k+2].y * w2.y + sv[k+2].z * w2.z + sv[k+2].w * w2.w;
            e3 += sv[k+3].x * w3.x + sv[k+3].y * w3.y + sv[k+3].z * w3.z + sv[k+3].w * w3.w;
        }
        acc += silu_f((e0 + e1) + (e2 + e3)) * Wattn[s_off + h];
    }

    // ---- node v -> registers ----
    float4 vv[12];
    {
        const float4* vp = (const float4*)(node_v + (size_t)n * (NV * 3));
        #pragma unroll
        for (int i = 0; i < 12; i++) vv[i] = vp[i];
    }

    // frame + pos -> registers
    const float* fb = frame + (size_t)n * 9;
    float ff0 = fb[0], ff1 = fb[1], ff2 = fb[2];
    float ff3 = fb[3], ff4 = fb[4], ff5 = fb[5];
    float ff6 = fb[6], ff7 = fb[7], ff8 = fb[8];
    const float* pb = pos + (size_t)n * 3;
    float ps0 = pb[0], ps1 = pb[1], ps2 = pb[2];

    // ---- vector GEMV + scalarize: rows h = q*4 .. q*4+3 ----
    #pragma unroll 2
    for (int j = 0; j < 4; j++){
        const int h = q * 4 + j;
        const float4* wvr = (const float4*)(Wv + h * NV);
        float a0 = 0.f, a1 = 0.f, a2 = 0.f;
        #pragma unroll
        for (int g = 0; g < 4; g++){            // vv = 4g .. 4g+3
            float4 x = vv[3*g + 0];
            float4 y = vv[3*g + 1];
            float4 z = vv[3*g + 2];
            float4 w = wvr[g];
            a0 += x.x * w.x + x.w * w.y + y.z * w.z + z.y * w.w;
            a1 += x.y * w.x + y.x * w.y + y.w * w.z + z.z * w.w;
            a2 += x.z * w.x + y.y * w.y + z.x * w.z + z.w * w.w;
        }
        float t0 = a0 * ff0 + a1 * ff3 + a2 * ff6;
        float t1 = a0 * ff1 + a1 * ff4 + a2 * ff7;
        float t2 = a0 * ff2 + a1 * ff5 + a2 * ff8;
        acc += silu_f(t0) * Wattn[v_off + h * 3 + 0]
             + silu_f(t1) * Wattn[v_off + h * 3 + 1]
             + silu_f(t2) * Wattn[v_off + h * 3 + 2];
    }

    // ---- combine the 4 row-partials (stays within the 4-lane group) ----
    acc += __shfl_xor(acc, 1);
    acc += __shfl_xor(acc, 2);

    // ---- store 32B pack: lanes q=0,1 write the two float4 halves ----
    if (q < 2){
        float4 o;
        if (q == 0){
            o = make_float4(acc,
                            packh2(ff0, ff1),
                            packh2(ff2, ff3),
                            packh2(ff4, ff5));
        } else {
            o = make_float4(packh2(ff6, ff7),
                            packh2(ff8, ps0),
                            packh2(ps1, ps2),
                            0.0f);
        }
        ((float4*)(pack + (size_t)n * 8))[q] = o;
    }
}

// Fused: raw -> exp -> ex[] ; also emits u16 copy of idx0. NO atomics.
__global__ __launch_bounds__(256) void edge_fused_kernel(
    const int* __restrict__ idx,
    const float* __restrict__ packA,
    const float* __restrict__ packB,
    const float* __restrict__ Wattn,
    float* __restrict__ ex,
    unsigned short* __restrict__ i016,
    int E)
{
    int e = blockIdx.x * 256 + threadIdx.x;
    if (e >= E) return;
    int i0 = __builtin_nontemporal_load(idx + e);
    int i1 = __builtin_nontemporal_load(idx + E + e);
    const float4* pa = (const float4*)(packA + (size_t)i0 * 8);
    const float4* pb = (const float4*)(packB + (size_t)i1 * 8);
    float4 a0 = pa[0], a1 = pa[1];
    float4 b0 = pb[0], b1 = pb[1];

    float2 t;
    t = unpackh2(a0.y); float af0 = t.x, af1 = t.y;
    t = unpackh2(a0.z); float af2 = t.x, af3 = t.y;
    t = unpackh2(a0.w); float af4 = t.x, af5 = t.y;
    t = unpackh2(a1.x); float af6 = t.x, af7 = t.y;
    t = unpackh2(a1.y); float af8 = t.x, ap0 = t.y;
    t = unpackh2(a1.z); float ap1 = t.x, ap2 = t.y;
    t = unpackh2(b0.y); float bf0 = t.x, bf1 = t.y;
    t = unpackh2(b0.z); float bf2 = t.x, bf3 = t.y;
    t = unpackh2(b0.w); float bf4 = t.x, bf5 = t.y;
    t = unpackh2(b1.x); float bf6 = t.x, bf7 = t.y;
    t = unpackh2(b1.y); float bf8 = t.x, bp0 = t.y;
    t = unpackh2(b1.z); float bp1 = t.x, bp2 = t.y;

    float d0 = bp0 - ap0, d1 = bp1 - ap1, d2 = bp2 - ap2;
    float pdf0 = d0*af0 + d1*af3 + d2*af6;
    float pdf1 = d0*af1 + d1*af4 + d2*af7;
    float pdf2 = d0*af2 + d1*af5 + d2*af8;
    float pdt0 = -(d0*bf0 + d1*bf3 + d2*bf6);
    float pdt1 = -(d0*bf1 + d1*bf4 + d2*bf7);
    float pdt2 = -(d0*bf2 + d1*bf5 + d2*bf8);

    float r = a0.x + b0.x;
    r += silu_f(pdf0) * Wattn[112] + silu_f(pdf1) * Wattn[113] + silu_f(pdf2) * Wattn[114];
    r += silu_f(pdt0) * Wattn[163] + silu_f(pdt1) * Wattn[164] + silu_f(pdt2) * Wattn[165];

    ex[e] = __expf(r);
    i016[e] = (unsigned short)i0;
}

// Ownership-partitioned segmented sum. Block (r, s): scans edge-slice s,
// LDS-accumulates nodes in range r, writes a non-atomic partial.
__global__ __launch_bounds__(512) void den_scan_kernel(
    const unsigned short* __restrict__ i016,
    const float* __restrict__ ex,
    float* __restrict__ den_part,     // [SPLITS][DP_STRIDE]
    int E, int N)
{
    const int s = blockIdx.x & (SPLITS - 1);   // low bits: XCD-affine slice reuse
    const int r = blockIdx.x / SPLITS;
    const int rn = (N + RANGES - 1) / RANGES;  // 6250 for N=50000
    const int base = r * rn;

    extern __shared__ float lden[];            // rn floats (25KB)
    for (int i = threadIdx.x; i < rn; i += 512) lden[i] = 0.0f;
    __syncthreads();

    const int es = (E + SPLITS - 1) / SPLITS;
    const int e0 = s * es;
    const int e1 = min(e0 + es, E);

    #pragma unroll 4
    for (int e = e0 + threadIdx.x; e < e1; e += 512){
        unsigned d = (unsigned)i016[e] - (unsigned)base;
        if (d < (unsigned)rn){
            atomicAdd(&lden[d], ex[e]);        // LDS atomic: fast HW path
        }
    }
    __syncthreads();

    float* dp = den_part + (size_t)s * DP_STRIDE + base;
    for (int i = threadIdx.x; i < rn && base + i < N; i += 512) dp[i] = lden[i];
}

// collapse the SPLITS partial sums; store reciprocal so edge_out multiplies
__global__ __launch_bounds__(256) void collapse_kernel(
    const float* __restrict__ den_part,
    float* __restrict__ inv_den,
    int N)
{
    int i = blockIdx.x * 256 + threadIdx.x;
    if (i >= N) return;
    float sum = 0.f;
    #pragma unroll
    for (int s = 0; s < SPLITS; s++)
        sum += __builtin_nontemporal_load(den_part + (size_t)s * DP_STRIDE + i);
    inv_den[i] = 1.0f / sum;
}

__global__ __launch_bounds__(256) void edge_out_kernel(
    const unsigned short* __restrict__ i016,
    const float* __restrict__ ex,
    const float* __restrict__ inv_den,
    float* __restrict__ out,
    int E)
{
    int e = blockIdx.x * 256 + threadIdx.x;
    if (e >= E) return;
    int i0 = (int)__builtin_nontemporal_load(i016 + e);
    float v = __builtin_nontemporal_load(ex + e) * inv_den[i0];
    __builtin_nontemporal_store(v, out + e);
}

extern "C" void kernel_launch(void* const* d_in, const int* in_sizes, int n_in,
                              void* d_out, int out_size, void* d_ws, size_t ws_size,
                              hipStream_t stream)
{
    const float* from_s  = (const float*)d_in[0];
    const float* from_v  = (const float*)d_in[1];
    const float* to_s    = (const float*)d_in[2];
    const float* to_v    = (const float*)d_in[3];
    const float* from_fr = (const float*)d_in[4];
    const float* to_fr   = (const float*)d_in[5];
    const float* from_p  = (const float*)d_in[6];
    const float* to_p    = (const float*)d_in[7];
    const float* Wfs     = (const float*)d_in[8];
    const float* Wts     = (const float*)d_in[9];
    const float* Wfv     = (const float*)d_in[10];
    const float* Wtv     = (const float*)d_in[11];
    const float* Wattn   = (const float*)d_in[12];
    const int*   idx     = (const int*)d_in[13];

    int N = in_sizes[0] / NS;
    int E = in_sizes[13] / 2;
    float* out = (float*)d_out;

    char* ws = (char*)d_ws;
    size_t packBytes = (size_t)N * 8 * sizeof(float);
    float*          packA    = (float*)(ws);
    float*          packB    = (float*)(ws + packBytes);
    float*          ex       = (float*)(ws + 2 * packBytes);
    float*          den_part = (float*)(ws + 2 * packBytes + (size_t)E * 4);
    float*          inv_den  = (float*)(ws + 2 * packBytes + (size_t)E * 4
                                         + (size_t)SPLITS * DP_STRIDE * 4);
    unsigned short* i016     = (unsigned short*)(ws + 2 * packBytes + (size_t)E * 4
                                         + (size_t)SPLITS * DP_STRIDE * 4
                                         + (size_t)N * 4 + 256);

    dim3 ngrid((4 * N + 255) / 256, 2);
    node_pack_kernel<<<ngrid, 256, 0, stream>>>(
        from_s, from_v, from_fr, from_p,
        to_s, to_v, to_fr, to_p,
        Wfs, Wts, Wfv, Wtv, Wattn,
        packA, packB, N);

    int nb_e = (E + 255) / 256;
    edge_fused_kernel<<<nb_e, 256, 0, stream>>>(idx, packA, packB, Wattn, ex, i016, E);

    int rn = (N + RANGES - 1) / RANGES;
    size_t lds_bytes = (size_t)rn * sizeof(float);
    den_scan_kernel<<<RANGES * SPLITS, 512, lds_bytes, stream>>>(i016, ex, den_part, E, N);
    collapse_kernel<<<(N + 255) / 256, 256, 0, stream>>>(den_part, inv_den, N);
    edge_out_kernel<<<nb_e, 256, 0, stream>>>(i016, ex, inv_den, out, E);
}

// Round 16
// 102.312 us; speedup vs baseline: 1.7953x; 1.7953x over previous
//
#include <hip/hip_runtime.h>
#include <hip/hip_fp16.h>
#include <math.h>

#define NS 64
#define NV 16
#define NHS 32
#define NHV 16

// den_scan geometry (unchanged)
#define RANGES 8
#define SPLITS 32
#define DP_STRIDE 50176

__device__ __forceinline__ float silu_f(float x){ return x * (1.0f / (1.0f + __expf(-x))); }

__device__ __forceinline__ float packh2(float a, float b){
    __half2 h = __floats2half2_rn(a, b);
    return __uint_as_float(*(unsigned*)&h);
}
__device__ __forceinline__ float2 unpackh2(float w){
    __half2 h = *(__half2*)&w;
    return __half22float2(h);
}

// Per-node precompute: pack[n] = 32B = {A fp32, ff[9]+pos[3] as fp16}
// WAVE-level h-split: block = 4 waves over the SAME 64 nodes (node = lane).
// Wave w owns scalar rows w*8..w*8+7 and vector rows w*4..w*4+3. The wave id
// is forced into an SGPR via readfirstlane so ALL weight addresses stay
// wave-uniform -> s_load (scalar pipe), amortized over 64 nodes/wave.
// Partials combined through a tiny LDS array (conflict-free).
__global__ __launch_bounds__(256) void node_pack_kernel(
    const float* __restrict__ from_s, const float* __restrict__ from_v,
    const float* __restrict__ from_fr, const float* __restrict__ from_p,
    const float* __restrict__ to_s, const float* __restrict__ to_v,
    const float* __restrict__ to_fr, const float* __restrict__ to_p,
    const float* __restrict__ Wfs, const float* __restrict__ Wts,
    const float* __restrict__ Wfv, const float* __restrict__ Wtv,
    const float* __restrict__ Wattn,
    float* __restrict__ packA, float* __restrict__ packB,
    int N)
{
    const int side = blockIdx.y;
    const float* node_s = side ? to_s  : from_s;
    const float* node_v = side ? to_v  : from_v;
    const float* frame  = side ? to_fr : from_fr;
    const float* pos    = side ? to_p  : from_p;
    const float* Ws     = side ? Wts   : Wfs;
    const float* Wv     = side ? Wtv   : Wfv;
    const int    s_off  = side ? 32 : 0;
    const int    v_off  = side ? 115 : 64;
    float*       pack   = side ? packB : packA;

    const int tid   = threadIdx.x;
    const int w     = __builtin_amdgcn_readfirstlane(tid >> 6);  // SGPR wave id
    const int n_loc = tid & 63;
    const int nbase = blockIdx.x * 64;
    const int n     = nbase + n_loc;

    __shared__ float part[3][64];

    float acc = 0.0f;
    float ff0=0,ff1=0,ff2=0,ff3=0,ff4=0,ff5=0,ff6=0,ff7=0,ff8=0;

    if (n < N){
        // ---- node s -> registers ----
        float4 sv[16];
        {
            const float4* sp = (const float4*)(node_s + (size_t)n * NS);
            #pragma unroll
            for (int i = 0; i < 16; i++) sv[i] = sp[i];
        }

        // ---- scalar rows h = w*8 .. w*8+7 (weights via s_load) ----
        #pragma unroll
        for (int i = 0; i < 8; i++){
            const float* wr = Ws + (w * 8 + i) * NS;   // uniform (w in SGPR)
            float e0 = 0.f, e1 = 0.f, e2 = 0.f, e3 = 0.f;
            #pragma unroll
            for (int k = 0; k < 16; k += 4){
                float4 s0 = sv[k], s1 = sv[k+1], s2 = sv[k+2], s3 = sv[k+3];
                e0 += s0.x * wr[4*k + 0]  + s0.y * wr[4*k + 1]  + s0.z * wr[4*k + 2]  + s0.w * wr[4*k + 3];
                e1 += s1.x * wr[4*k + 4]  + s1.y * wr[4*k + 5]  + s1.z * wr[4*k + 6]  + s1.w * wr[4*k + 7];
                e2 += s2.x * wr[4*k + 8]  + s2.y * wr[4*k + 9]  + s2.z * wr[4*k + 10] + s2.w * wr[4*k + 11];
                e3 += s3.x * wr[4*k + 12] + s3.y * wr[4*k + 13] + s3.z * wr[4*k + 14] + s3.w * wr[4*k + 15];
            }
            acc += silu_f((e0 + e1) + (e2 + e3)) * Wattn[s_off + w * 8 + i];
        }

        // ---- node v + frame -> registers (sv now dead; regs reused) ----
        float4 vv[12];
        {
            const float4* vp = (const float4*)(node_v + (size_t)n * (NV * 3));
            #pragma unroll
            for (int i = 0; i < 12; i++) vv[i] = vp[i];
        }
        const float* fb = frame + (size_t)n * 9;
        ff0 = fb[0]; ff1 = fb[1]; ff2 = fb[2];
        ff3 = fb[3]; ff4 = fb[4]; ff5 = fb[5];
        ff6 = fb[6]; ff7 = fb[7]; ff8 = fb[8];

        // ---- vector rows hv = w*4 .. w*4+3 (weights via s_load) ----
        #pragma unroll
        for (int j = 0; j < 4; j++){
            const int hv = w * 4 + j;                  // uniform
            const float* wvr = Wv + hv * NV;
            float a0 = 0.f, a1 = 0.f, a2 = 0.f;
            #pragma unroll
            for (int g = 0; g < 4; g++){
                float4 x = vv[3*g + 0];
                float4 y = vv[3*g + 1];
                float4 z = vv[3*g + 2];
                float w0 = wvr[4*g + 0], w1 = wvr[4*g + 1];
                float w2 = wvr[4*g + 2], w3 = wvr[4*g + 3];
                a0 += x.x * w0 + x.w * w1 + y.z * w2 + z.y * w3;
                a1 += x.y * w0 + y.x * w1 + y.w * w2 + z.z * w3;
                a2 += x.z * w0 + y.y * w1 + z.x * w2 + z.w * w3;
            }
            float t0 = a0 * ff0 + a1 * ff3 + a2 * ff6;
            float t1 = a0 * ff1 + a1 * ff4 + a2 * ff7;
            float t2 = a0 * ff2 + a1 * ff5 + a2 * ff8;
            acc += silu_f(t0) * Wattn[v_off + hv * 3 + 0]
                 + silu_f(t1) * Wattn[v_off + hv * 3 + 1]
                 + silu_f(t2) * Wattn[v_off + hv * 3 + 2];
        }
    }

    // ---- combine wave partials through LDS ----
    if (w != 0){
        if (n < N) part[w - 1][n_loc] = acc;
    }
    __syncthreads();

    if (w == 0 && n < N){
        acc += part[0][n_loc] + part[1][n_loc] + part[2][n_loc];
        const float* pb = pos + (size_t)n * 3;
        float ps0 = pb[0], ps1 = pb[1], ps2 = pb[2];
        float4* pk = (float4*)(pack + (size_t)n * 8);
        pk[0] = make_float4(acc,
                            packh2(ff0, ff1),
                            packh2(ff2, ff3),
                            packh2(ff4, ff5));
        pk[1] = make_float4(packh2(ff6, ff7),
                            packh2(ff8, ps0),
                            packh2(ps1, ps2),
                            0.0f);
    }
}

// Fused: raw -> exp -> ex[] ; also emits u16 copy of idx0. NO atomics.
__global__ __launch_bounds__(256) void edge_fused_kernel(
    const int* __restrict__ idx,
    const float* __restrict__ packA,
    const float* __restrict__ packB,
    const float* __restrict__ Wattn,
    float* __restrict__ ex,
    unsigned short* __restrict__ i016,
    int E)
{
    int e = blockIdx.x * 256 + threadIdx.x;
    if (e >= E) return;
    int i0 = __builtin_nontemporal_load(idx + e);
    int i1 = __builtin_nontemporal_load(idx + E + e);
    const float4* pa = (const float4*)(packA + (size_t)i0 * 8);
    const float4* pb = (const float4*)(packB + (size_t)i1 * 8);
    float4 a0 = pa[0], a1 = pa[1];
    float4 b0 = pb[0], b1 = pb[1];

    float2 t;
    t = unpackh2(a0.y); float af0 = t.x, af1 = t.y;
    t = unpackh2(a0.z); float af2 = t.x, af3 = t.y;
    t = unpackh2(a0.w); float af4 = t.x, af5 = t.y;
    t = unpackh2(a1.x); float af6 = t.x, af7 = t.y;
    t = unpackh2(a1.y); float af8 = t.x, ap0 = t.y;
    t = unpackh2(a1.z); float ap1 = t.x, ap2 = t.y;
    t = unpackh2(b0.y); float bf0 = t.x, bf1 = t.y;
    t = unpackh2(b0.z); float bf2 = t.x, bf3 = t.y;
    t = unpackh2(b0.w); float bf4 = t.x, bf5 = t.y;
    t = unpackh2(b1.x); float bf6 = t.x, bf7 = t.y;
    t = unpackh2(b1.y); float bf8 = t.x, bp0 = t.y;
    t = unpackh2(b1.z); float bp1 = t.x, bp2 = t.y;

    float d0 = bp0 - ap0, d1 = bp1 - ap1, d2 = bp2 - ap2;
    float pdf0 = d0*af0 + d1*af3 + d2*af6;
    float pdf1 = d0*af1 + d1*af4 + d2*af7;
    float pdf2 = d0*af2 + d1*af5 + d2*af8;
    float pdt0 = -(d0*bf0 + d1*bf3 + d2*bf6);
    float pdt1 = -(d0*bf1 + d1*bf4 + d2*bf7);
    float pdt2 = -(d0*bf2 + d1*bf5 + d2*bf8);

    float r = a0.x + b0.x;
    r += silu_f(pdf0) * Wattn[112] + silu_f(pdf1) * Wattn[113] + silu_f(pdf2) * Wattn[114];
    r += silu_f(pdt0) * Wattn[163] + silu_f(pdt1) * Wattn[164] + silu_f(pdt2) * Wattn[165];

    ex[e] = __expf(r);
    i016[e] = (unsigned short)i0;
}

// Ownership-partitioned segmented sum. Block (r, s): scans edge-slice s,
// LDS-accumulates nodes in range r, writes a non-atomic partial.
__global__ __launch_bounds__(512) void den_scan_kernel(
    const unsigned short* __restrict__ i016,
    const float* __restrict__ ex,
    float* __restrict__ den_part,     // [SPLITS][DP_STRIDE]
    int E, int N)
{
    const int s = blockIdx.x & (SPLITS - 1);   // low bits: XCD-affine slice reuse
    const int r = blockIdx.x / SPLITS;
    const int rn = (N + RANGES - 1) / RANGES;  // 6250 for N=50000
    const int base = r * rn;

    extern __shared__ float lden[];            // rn floats (25KB)
    for (int i = threadIdx.x; i < rn; i += 512) lden[i] = 0.0f;
    __syncthreads();

    const int es = (E + SPLITS - 1) / SPLITS;
    const int e0 = s * es;
    const int e1 = min(e0 + es, E);

    #pragma unroll 4
    for (int e = e0 + threadIdx.x; e < e1; e += 512){
        unsigned d = (unsigned)i016[e] - (unsigned)base;
        if (d < (unsigned)rn){
            atomicAdd(&lden[d], ex[e]);        // LDS atomic: fast HW path
        }
    }
    __syncthreads();

    float* dp = den_part + (size_t)s * DP_STRIDE + base;
    for (int i = threadIdx.x; i < rn && base + i < N; i += 512) dp[i] = lden[i];
}

// collapse the SPLITS partial sums; store reciprocal so edge_out multiplies
__global__ __launch_bounds__(256) void collapse_kernel(
    const float* __restrict__ den_part,
    float* __restrict__ inv_den,
    int N)
{
    int i = blockIdx.x * 256 + threadIdx.x;
    if (i >= N) return;
    float sum = 0.f;
    #pragma unroll
    for (int s = 0; s < SPLITS; s++)
        sum += __builtin_nontemporal_load(den_part + (size_t)s * DP_STRIDE + i);
    inv_den[i] = 1.0f / sum;
}

__global__ __launch_bounds__(256) void edge_out_kernel(
    const unsigned short* __restrict__ i016,
    const float* __restrict__ ex,
    const float* __restrict__ inv_den,
    float* __restrict__ out,
    int E)
{
    int e = blockIdx.x * 256 + threadIdx.x;
    if (e >= E) return;
    int i0 = (int)__builtin_nontemporal_load(i016 + e);
    float v = __builtin_nontemporal_load(ex + e) * inv_den[i0];
    __builtin_nontemporal_store(v, out + e);
}

extern "C" void kernel_launch(void* const* d_in, const int* in_sizes, int n_in,
                              void* d_out, int out_size, void* d_ws, size_t ws_size,
                              hipStream_t stream)
{
    const float* from_s  = (const float*)d_in[0];
    const float* from_v  = (const float*)d_in[1];
    const float* to_s    = (const float*)d_in[2];
    const float* to_v    = (const float*)d_in[3];
    const float* from_fr = (const float*)d_in[4];
    const float* to_fr   = (const float*)d_in[5];
    const float* from_p  = (const float*)d_in[6];
    const float* to_p    = (const float*)d_in[7];
    const float* Wfs     = (const float*)d_in[8];
    const float* Wts     = (const float*)d_in[9];
    const float* Wfv     = (const float*)d_in[10];
    const float* Wtv     = (const float*)d_in[11];
    const float* Wattn   = (const float*)d_in[12];
    const int*   idx     = (const int*)d_in[13];

    int N = in_sizes[0] / NS;
    int E = in_sizes[13] / 2;
    float* out = (float*)d_out;

    char* ws = (char*)d_ws;
    size_t packBytes = (size_t)N * 8 * sizeof(float);
    float*          packA    = (float*)(ws);
    float*          packB    = (float*)(ws + packBytes);
    float*          ex       = (float*)(ws + 2 * packBytes);
    float*          den_part = (float*)(ws + 2 * packBytes + (size_t)E * 4);
    float*          inv_den  = (float*)(ws + 2 * packBytes + (size_t)E * 4
                                         + (size_t)SPLITS * DP_STRIDE * 4);
    unsigned short* i016     = (unsigned short*)(ws + 2 * packBytes + (size_t)E * 4
                                         + (size_t)SPLITS * DP_STRIDE * 4
                                         + (size_t)N * 4 + 256);

    dim3 ngrid((N + 63) / 64, 2);
    node_pack_kernel<<<ngrid, 256, 0, stream>>>(
        from_s, from_v, from_fr, from_p,
        to_s, to_v, to_fr, to_p,
        Wfs, Wts, Wfv, Wtv, Wattn,
        packA, packB, N);

    int nb_e = (E + 255) / 256;
    edge_fused_kernel<<<nb_e, 256, 0, stream>>>(idx, packA, packB, Wattn, ex, i016, E);

    int rn = (N + RANGES - 1) / RANGES;
    size_t lds_bytes = (size_t)rn * sizeof(float);
    den_scan_kernel<<<RANGES * SPLITS, 512, lds_bytes, stream>>>(i016, ex, den_part, E, N);
    collapse_kernel<<<(N + 255) / 256, 256, 0, stream>>>(den_part, inv_den, N);
    edge_out_kernel<<<nb_e, 256, 0, stream>>>(i016, ex, inv_den, out, E);
}

// Round 17
// 73.073 us; speedup vs baseline: 2.5137x; 1.4001x over previous
//
#include <hip/hip_runtime.h>
#include <hip/hip_fp16.h>
#include <math.h>

#define NS 64
#define NV 16
#define NHS 32
#define NHV 16

// den_scan geometry (unchanged)
#define RANGES 8
#define SPLITS 32
#define DP_STRIDE 50176

typedef __attribute__((ext_vector_type(8))) short short8;
typedef __attribute__((ext_vector_type(4))) float f32x4;

__device__ __forceinline__ float silu_f(float x){ return x * (1.0f / (1.0f + __expf(-x))); }

__device__ __forceinline__ float packh2(float a, float b){
    __half2 h = __floats2half2_rn(a, b);
    return __uint_as_float(*(unsigned*)&h);
}
__device__ __forceinline__ float2 unpackh2(float w){
    __half2 h = *(__half2*)&w;
    return __half22float2(h);
}

// fp32 -> bf16 with round-to-nearest-even
__device__ __forceinline__ unsigned short f2b(float x){
    unsigned u = __float_as_uint(x);
    unsigned r = (u + 0x7FFFu + ((u >> 16) & 1u)) >> 16;
    return (unsigned short)r;
}

// Per-node precompute: pack[n] = 32B = {A fp32, ff[9]+pos[3] as fp16}
// MFMA version: block = 4 waves x 64 nodes. Scalar GEMV = 4 mfma_16x16x32_bf16
// (2 h-tiles x 2 K-steps), vector GEMV = 3 mfma (K zero-padded 16->32).
// B-frags (weights) live in registers, loaded once per block. D layout
// (m89-verified): col = lane&15 = h, row = (lane>>4)*4 + reg = node.
__global__ __launch_bounds__(256) void node_pack_kernel(
    const float* __restrict__ from_s, const float* __restrict__ from_v,
    const float* __restrict__ from_fr, const float* __restrict__ from_p,
    const float* __restrict__ to_s, const float* __restrict__ to_v,
    const float* __restrict__ to_fr, const float* __restrict__ to_p,
    const float* __restrict__ Wfs, const float* __restrict__ Wts,
    const float* __restrict__ Wfv, const float* __restrict__ Wtv,
    const float* __restrict__ Wattn,
    float* __restrict__ packA, float* __restrict__ packB,
    int N)
{
    const int side = blockIdx.y;
    const float* node_s = side ? to_s  : from_s;
    const float* node_v = side ? to_v  : from_v;
    const float* frame  = side ? to_fr : from_fr;
    const float* pos    = side ? to_p  : from_p;
    const float* Ws     = side ? Wts   : Wfs;
    const float* Wv     = side ? Wtv   : Wfv;
    const int    s_off  = side ? 32 : 0;
    const int    v_off  = side ? 115 : 64;
    float*       pack   = side ? packB : packA;

    __shared__ unsigned short lsA[64 * 72];     // s tile bf16, stride 72 (144B rows)
    __shared__ unsigned short lsV[3 * 64 * 24]; // v tile bf16 [c][node][vv], stride 24
    __shared__ float lfp[64 * 13];              // frame(9)+pos(3) fp32, stride 13
    __shared__ float lacc[64];

    const int tid  = threadIdx.x;
    const int lane = tid & 63;
    const int w    = tid >> 6;
    const int nbase = blockIdx.x * 64;
    const int cnt = min(64, N - nbase);

    // ---- stage node data -> LDS (coalesced global reads, bf16 convert) ----
    {
        const float4* sp = (const float4*)(node_s + (size_t)nbase * NS);
        for (int i4 = tid; i4 < cnt * 16; i4 += 256){
            float4 x = sp[i4];
            unsigned short* d = lsA + (i4 >> 4) * 72 + (i4 & 15) * 4;
            d[0] = f2b(x.x); d[1] = f2b(x.y); d[2] = f2b(x.z); d[3] = f2b(x.w);
        }
        const float* vp0 = node_v + (size_t)nbase * (NV * 3);
        for (int i = tid; i < cnt * 48; i += 256){
            int n = i / 48, rem = i - n * 48;
            int vv = rem / 3, c = rem - vv * 3;
            lsV[c * 1536 + n * 24 + vv] = f2b(vp0[i]);
        }
        for (int i = tid; i < cnt * 9; i += 256)
            lfp[(i / 9) * 13 + (i % 9)] = frame[(size_t)nbase * 9 + i];
        for (int i = tid; i < cnt * 3; i += 256)
            lfp[(i / 3) * 13 + 9 + (i % 3)] = pos[(size_t)nbase * 3 + i];
    }

    // ---- B-frags + Wattn -> registers (identical in all waves) ----
    const int h  = lane & 15;       // B col / D col
    const int kq = lane >> 4;       // k-quarter
    const int k0 = kq * 8;

    short8 Bs[2][2];                // [h-tile][k-step]
    #pragma unroll
    for (int t = 0; t < 2; t++){
        #pragma unroll
        for (int s = 0; s < 2; s++){
            const float4* wp = (const float4*)(Ws + (t * 16 + h) * NS + s * 32 + k0);
            float4 x = wp[0], y = wp[1];
            short8 b;
            b[0] = (short)f2b(x.x); b[1] = (short)f2b(x.y);
            b[2] = (short)f2b(x.z); b[3] = (short)f2b(x.w);
            b[4] = (short)f2b(y.x); b[5] = (short)f2b(y.y);
            b[6] = (short)f2b(y.z); b[7] = (short)f2b(y.w);
            Bs[t][s] = b;
        }
    }
    short8 Bv = {0,0,0,0,0,0,0,0};
    if (k0 < 16){
        const float4* wp = (const float4*)(Wv + h * NV + k0);
        float4 x = wp[0], y = wp[1];
        short8 b;
        b[0] = (short)f2b(x.x); b[1] = (short)f2b(x.y);
        b[2] = (short)f2b(x.z); b[3] = (short)f2b(x.w);
        b[4] = (short)f2b(y.x); b[5] = (short)f2b(y.y);
        b[6] = (short)f2b(y.z); b[7] = (short)f2b(y.w);
        Bv = b;
    }
    const float waS0 = Wattn[s_off + h];
    const float waS1 = Wattn[s_off + 16 + h];
    const float waV0 = Wattn[v_off + h * 3 + 0];
    const float waV1 = Wattn[v_off + h * 3 + 1];
    const float waV2 = Wattn[v_off + h * 3 + 2];

    __syncthreads();

    // ---- MFMA: this wave's 16 nodes (rows rbase..rbase+15) ----
    const int rbase = w * 16;
    const unsigned short* arow = lsA + (rbase + h) * 72;    // A row = lane&15
    short8 A0 = *(const short8*)(arow + k0);                // k-step 0
    short8 A1 = *(const short8*)(arow + 32 + k0);           // k-step 1
    f32x4 zz = {0.f, 0.f, 0.f, 0.f};
    f32x4 D0 = __builtin_amdgcn_mfma_f32_16x16x32_bf16(A0, Bs[0][0], zz, 0, 0, 0);
    D0       = __builtin_amdgcn_mfma_f32_16x16x32_bf16(A1, Bs[0][1], D0, 0, 0, 0);
    f32x4 D1 = __builtin_amdgcn_mfma_f32_16x16x32_bf16(A0, Bs[1][0], zz, 0, 0, 0);
    D1       = __builtin_amdgcn_mfma_f32_16x16x32_bf16(A1, Bs[1][1], D1, 0, 0, 0);

    short8 zero8 = {0,0,0,0,0,0,0,0};
    f32x4 D2[3];
    #pragma unroll
    for (int c = 0; c < 3; c++){
        short8 Ac = zero8;
        if (k0 < 16)
            Ac = *(const short8*)(lsV + c * 1536 + (rbase + h) * 24 + k0);
        D2[c] = __builtin_amdgcn_mfma_f32_16x16x32_bf16(Ac, Bv, zz, 0, 0, 0);
    }

    // ---- epilogue: silu + Wattn dot + h-reduce ----
    #pragma unroll
    for (int r = 0; r < 4; r++){
        int nl = rbase + kq * 4 + r;            // D row = node
        float d0 = D0[r], d1 = D1[r];
        float a0 = D2[0][r], a1 = D2[1][r], a2 = D2[2][r];
        const float* fb = lfp + nl * 13;
        float t0 = a0 * fb[0] + a1 * fb[3] + a2 * fb[6];
        float t1 = a0 * fb[1] + a1 * fb[4] + a2 * fb[7];
        float t2 = a0 * fb[2] + a1 * fb[5] + a2 * fb[8];
        float contrib = silu_f(d0) * waS0 + silu_f(d1) * waS1
                      + silu_f(t0) * waV0 + silu_f(t1) * waV1 + silu_f(t2) * waV2;
        contrib += __shfl_xor(contrib, 1, 16);
        contrib += __shfl_xor(contrib, 2, 16);
        contrib += __shfl_xor(contrib, 4, 16);
        contrib += __shfl_xor(contrib, 8, 16);
        if (h == 0) lacc[nl] = contrib;
    }
    __syncthreads();

    // ---- pack store: 2 threads per node, fully coalesced ----
    if (tid < 128){
        int nl = tid >> 1, half = tid & 1;
        if (nl < cnt){
            const float* fb = lfp + nl * 13;
            float4 o;
            if (half == 0){
                o = make_float4(lacc[nl],
                                packh2(fb[0], fb[1]),
                                packh2(fb[2], fb[3]),
                                packh2(fb[4], fb[5]));
            } else {
                o = make_float4(packh2(fb[6], fb[7]),
                                packh2(fb[8], fb[9]),
                                packh2(fb[10], fb[11]),
                                0.0f);
            }
            ((float4*)(pack + (size_t)(nbase + nl) * 8))[half] = o;
        }
    }
}

// Fused: raw -> exp -> ex[] ; also emits u16 copy of idx0. NO atomics.
__global__ __launch_bounds__(256) void edge_fused_kernel(
    const int* __restrict__ idx,
    const float* __restrict__ packA,
    const float* __restrict__ packB,
    const float* __restrict__ Wattn,
    float* __restrict__ ex,
    unsigned short* __restrict__ i016,
    int E)
{
    int e = blockIdx.x * 256 + threadIdx.x;
    if (e >= E) return;
    int i0 = __builtin_nontemporal_load(idx + e);
    int i1 = __builtin_nontemporal_load(idx + E + e);
    const float4* pa = (const float4*)(packA + (size_t)i0 * 8);
    const float4* pb = (const float4*)(packB + (size_t)i1 * 8);
    float4 a0 = pa[0], a1 = pa[1];
    float4 b0 = pb[0], b1 = pb[1];

    float2 t;
    t = unpackh2(a0.y); float af0 = t.x, af1 = t.y;
    t = unpackh2(a0.z); float af2 = t.x, af3 = t.y;
    t = unpackh2(a0.w); float af4 = t.x, af5 = t.y;
    t = unpackh2(a1.x); float af6 = t.x, af7 = t.y;
    t = unpackh2(a1.y); float af8 = t.x, ap0 = t.y;
    t = unpackh2(a1.z); float ap1 = t.x, ap2 = t.y;
    t = unpackh2(b0.y); float bf0 = t.x, bf1 = t.y;
    t = unpackh2(b0.z); float bf2 = t.x, bf3 = t.y;
    t = unpackh2(b0.w); float bf4 = t.x, bf5 = t.y;
    t = unpackh2(b1.x); float bf6 = t.x, bf7 = t.y;
    t = unpackh2(b1.y); float bf8 = t.x, bp0 = t.y;
    t = unpackh2(b1.z); float bp1 = t.x, bp2 = t.y;

    float d0 = bp0 - ap0, d1 = bp1 - ap1, d2 = bp2 - ap2;
    float pdf0 = d0*af0 + d1*af3 + d2*af6;
    float pdf1 = d0*af1 + d1*af4 + d2*af7;
    float pdf2 = d0*af2 + d1*af5 + d2*af8;
    float pdt0 = -(d0*bf0 + d1*bf3 + d2*bf6);
    float pdt1 = -(d0*bf1 + d1*bf4 + d2*bf7);
    float pdt2 = -(d0*bf2 + d1*bf5 + d2*bf8);

    float r = a0.x + b0.x;
    r += silu_f(pdf0) * Wattn[112] + silu_f(pdf1) * Wattn[113] + silu_f(pdf2) * Wattn[114];
    r += silu_f(pdt0) * Wattn[163] + silu_f(pdt1) * Wattn[164] + silu_f(pdt2) * Wattn[165];

    ex[e] = __expf(r);
    i016[e] = (unsigned short)i0;
}

// Ownership-partitioned segmented sum. Block (r, s): scans edge-slice s,
// LDS-accumulates nodes in range r, writes a non-atomic partial.
__global__ __launch_bounds__(512) void den_scan_kernel(
    const unsigned short* __restrict__ i016,
    const float* __restrict__ ex,
    float* __restrict__ den_part,     // [SPLITS][DP_STRIDE]
    int E, int N)
{
    const int s = blockIdx.x & (SPLITS - 1);   // low bits: XCD-affine slice reuse
    const int r = blockIdx.x / SPLITS;
    const int rn = (N + RANGES - 1) / RANGES;  // 6250 for N=50000
    const int base = r * rn;

    extern __shared__ float lden[];            // rn floats (25KB)
    for (int i = threadIdx.x; i < rn; i += 512) lden[i] = 0.0f;
    __syncthreads();

    const int es = (E + SPLITS - 1) / SPLITS;
    const int e0 = s * es;
    const int e1 = min(e0 + es, E);

    #pragma unroll 4
    for (int e = e0 + threadIdx.x; e < e1; e += 512){
        unsigned d = (unsigned)i016[e] - (unsigned)base;
        if (d < (unsigned)rn){
            atomicAdd(&lden[d], ex[e]);        // LDS atomic: fast HW path
        }
    }
    __syncthreads();

    float* dp = den_part + (size_t)s * DP_STRIDE + base;
    for (int i = threadIdx.x; i < rn && base + i < N; i += 512) dp[i] = lden[i];
}

// collapse the SPLITS partial sums; store reciprocal so edge_out multiplies
__global__ __launch_bounds__(256) void collapse_kernel(
    const float* __restrict__ den_part,
    float* __restrict__ inv_den,
    int N)
{
    int i = blockIdx.x * 256 + threadIdx.x;
    if (i >= N) return;
    float sum = 0.f;
    #pragma unroll
    for (int s = 0; s < SPLITS; s++)
        sum += __builtin_nontemporal_load(den_part + (size_t)s * DP_STRIDE + i);
    inv_den[i] = 1.0f / sum;
}

__global__ __launch_bounds__(256) void edge_out_kernel(
    const unsigned short* __restrict__ i016,
    const float* __restrict__ ex,
    const float* __restrict__ inv_den,
    float* __restrict__ out,
    int E)
{
    int e = blockIdx.x * 256 + threadIdx.x;
    if (e >= E) return;
    int i0 = (int)__builtin_nontemporal_load(i016 + e);
    float v = __builtin_nontemporal_load(ex + e) * inv_den[i0];
    __builtin_nontemporal_store(v, out + e);
}

extern "C" void kernel_launch(void* const* d_in, const int* in_sizes, int n_in,
                              void* d_out, int out_size, void* d_ws, size_t ws_size,
                              hipStream_t stream)
{
    const float* from_s  = (const float*)d_in[0];
    const float* from_v  = (const float*)d_in[1];
    const float* to_s    = (const float*)d_in[2];
    const float* to_v    = (const float*)d_in[3];
    const float* from_fr = (const float*)d_in[4];
    const float* to_fr   = (const float*)d_in[5];
    const float* from_p  = (const float*)d_in[6];
    const float* to_p    = (const float*)d_in[7];
    const float* Wfs     = (const float*)d_in[8];
    const float* Wts     = (const float*)d_in[9];
    const float* Wfv     = (const float*)d_in[10];
    const float* Wtv     = (const float*)d_in[11];
    const float* Wattn   = (const float*)d_in[12];
    const int*   idx     = (const int*)d_in[13];

    int N = in_sizes[0] / NS;
    int E = in_sizes[13] / 2;
    float* out = (float*)d_out;

    char* ws = (char*)d_ws;
    size_t packBytes = (size_t)N * 8 * sizeof(float);
    float*          packA    = (float*)(ws);
    float*          packB    = (float*)(ws + packBytes);
    float*          ex       = (float*)(ws + 2 * packBytes);
    float*          den_part = (float*)(ws + 2 * packBytes + (size_t)E * 4);
    float*          inv_den  = (float*)(ws + 2 * packBytes + (size_t)E * 4
                                         + (size_t)SPLITS * DP_STRIDE * 4);
    unsigned short* i016     = (unsigned short*)(ws + 2 * packBytes + (size_t)E * 4
                                         + (size_t)SPLITS * DP_STRIDE * 4
                                         + (size_t)N * 4 + 256);

    dim3 ngrid((N + 63) / 64, 2);
    node_pack_kernel<<<ngrid, 256, 0, stream>>>(
        from_s, from_v, from_fr, from_p,
        to_s, to_v, to_fr, to_p,
        Wfs, Wts, Wfv, Wtv, Wattn,
        packA, packB, N);

    int nb_e = (E + 255) / 256;
    edge_fused_kernel<<<nb_e, 256, 0, stream>>>(idx, packA, packB, Wattn, ex, i016, E);

    int rn = (N + RANGES - 1) / RANGES;
    size_t lds_bytes = (size_t)rn * sizeof(float);
    den_scan_kernel<<<RANGES * SPLITS, 512, lds_bytes, stream>>>(i016, ex, den_part, E, N);
    collapse_kernel<<<(N + 255) / 256, 256, 0, stream>>>(den_part, inv_den, N);
    edge_out_kernel<<<nb_e, 256, 0, stream>>>(i016, ex, inv_den, out, E);
}